// Round 8
// baseline (125.794 us; speedup 1.0000x reference)
//
#include <hip/hip_runtime.h>
#include <stdint.h>

typedef int   i32x8 __attribute__((ext_vector_type(8)));
typedef float f32x4 __attribute__((ext_vector_type(4)));

#define B_ROWS 8192
#define D_DIM  512
#define BM 256
#define BN 256
#define BK 128
#define N_BLOCKS 1024   // (8192/256)^2

// monotone float<->uint encoding: enc order == float order (so uint atomicMin
// == float min). f>=0: set sign bit; f<0: bitwise NOT.
__device__ __forceinline__ uint32_t enc_f32(float f) {
  uint32_t s = __float_as_uint(f);
  return (s & 0x80000000u) ? ~s : (s | 0x80000000u);
}
__device__ __forceinline__ float dec_f32(uint32_t e) {
  uint32_t s = (e & 0x80000000u) ? (e ^ 0x80000000u) : ~e;
  return __uint_as_float(s);
}

// ---------------------------------------------------------------------------
// Kernel 1: per-row normalize (fp32 -> fp8 e4m3) + cos(anchor, positive).
// Wave per row. Also inits minenc[r] = +inf encoding (replaces a memset node).
// ---------------------------------------------------------------------------
__global__ __launch_bounds__(256) void norm_kernel(
    const float* __restrict__ anchor, const float* __restrict__ positive,
    uint32_t* __restrict__ a8, uint32_t* __restrict__ p8,
    float* __restrict__ cos_ap, uint32_t* __restrict__ minenc)
{
  const int wave = threadIdx.x >> 6, lane = threadIdx.x & 63;
  const int r = blockIdx.x * 4 + wave;

  const float4* av = (const float4*)(anchor   + (size_t)r * D_DIM) + lane * 2;
  const float4* pv = (const float4*)(positive + (size_t)r * D_DIM) + lane * 2;
  float4 a0 = av[0], a1 = av[1];
  float4 p0 = pv[0], p1 = pv[1];

  float sa = a0.x*a0.x + a0.y*a0.y + a0.z*a0.z + a0.w*a0.w
           + a1.x*a1.x + a1.y*a1.y + a1.z*a1.z + a1.w*a1.w;
  float sp = p0.x*p0.x + p0.y*p0.y + p0.z*p0.z + p0.w*p0.w
           + p1.x*p1.x + p1.y*p1.y + p1.z*p1.z + p1.w*p1.w;
  float dp = a0.x*p0.x + a0.y*p0.y + a0.z*p0.z + a0.w*p0.w
           + a1.x*p1.x + a1.y*p1.y + a1.z*p1.z + a1.w*p1.w;

#pragma unroll
  for (int d = 1; d < 64; d <<= 1) {
    sa += __shfl_xor(sa, d);
    sp += __shfl_xor(sp, d);
    dp += __shfl_xor(dp, d);
  }

  const float na = sqrtf(sa), np = sqrtf(sp);
  const float ia = 1.0f / na, ip = 1.0f / np;

  float na0 = a0.x*ia, na1 = a0.y*ia, na2 = a0.z*ia, na3 = a0.w*ia;
  float na4 = a1.x*ia, na5 = a1.y*ia, na6 = a1.z*ia, na7 = a1.w*ia;
  float np0 = p0.x*ip, np1 = p0.y*ip, np2 = p0.z*ip, np3 = p0.w*ip;
  float np4 = p1.x*ip, np5 = p1.y*ip, np6 = p1.z*ip, np7 = p1.w*ip;

  uint32_t aw0 = __builtin_amdgcn_cvt_pk_fp8_f32(na0, na1, 0,  false);
  aw0          = __builtin_amdgcn_cvt_pk_fp8_f32(na2, na3, aw0, true);
  uint32_t aw1 = __builtin_amdgcn_cvt_pk_fp8_f32(na4, na5, 0,  false);
  aw1          = __builtin_amdgcn_cvt_pk_fp8_f32(na6, na7, aw1, true);
  uint32_t pw0 = __builtin_amdgcn_cvt_pk_fp8_f32(np0, np1, 0,  false);
  pw0          = __builtin_amdgcn_cvt_pk_fp8_f32(np2, np3, pw0, true);
  uint32_t pw1 = __builtin_amdgcn_cvt_pk_fp8_f32(np4, np5, 0,  false);
  pw1          = __builtin_amdgcn_cvt_pk_fp8_f32(np6, np7, pw1, true);

  ((uint2*)a8)[(size_t)r * 64 + lane] = make_uint2(aw0, aw1);
  ((uint2*)p8)[(size_t)r * 64 + lane] = make_uint2(pw0, pw1);

  if (lane == 0) {
    cos_ap[r] = dp / fmaxf(na * np, 1e-8f);
    minenc[r] = 0xFFFFFFFFu;   // +inf in monotone encoding
  }
}

// ---------------------------------------------------------------------------
// global -> LDS direct load, 16B per lane (dest = wave-uniform base + lane*16).
// ---------------------------------------------------------------------------
__device__ __forceinline__ void load16_to_lds(const void* g, void* l) {
  __builtin_amdgcn_global_load_lds(
      (__attribute__((address_space(1))) uint32_t*)(uintptr_t)(g),
      (__attribute__((address_space(3))) uint32_t*)(uintptr_t)(l),
      16, 0, 0);
}

// ---------------------------------------------------------------------------
// Kernel 2: 256x256 fp8 MX-MFMA tile of sim = A_n * P_n^T (scale=1.0), fused
// diagonal-masked row-min -> device atomicMin on encoded floats.
//
// R8: unpinned 8-phase schedule. R7 (16 tiny phases, sched_barrier(0) +
// asm lgkmcnt(0) each) stalled at MfmaUtil 24% -- the pins forbade the
// compiler's counted lgkm interleave (m141 precedent: order-pinning costs
// 1.7x), and 8-MFMA windows gave a poor duty cycle. R8: 2 phases per K-tile
// (16 MFMAs each), NO sched_barrier / NO explicit lgkm asm (compiler emits
// counted lgkmcnt and may overlap ds_reads with MFMAs), raw s_barriers +
// setprio(1) around each MFMA cluster kept, R7's verified staging ledger
// kept: prologue stages t0+t1 + vmcnt(8); t2 staged in tile1 phase tops,
// t3 in tile2 (WAR-safe: a wave at a closing barrier has consumed, hence
// retired, all its reads of the buffer being re-staged); tail vmcnt(0) only
// at t<3 tile ends where loads have >=1 phase of cover.
//   Settled: A must be LDS-staged (R2/R4/R5); no device fences in simmin
//   (R3/R4: -340us); drains with cover are free, naked L2 latency is not.
// Fragment/swizzle/epilogue math byte-identical to verified R6/R7.
//
// Block swizzle: xcd = bid&7 owns A-rowTiles [xcd*4, xcd*4+4) for ALL 32
// colTiles (A slice 512 KB/XCD stays L2-resident; P streams 4 MB/XCD).
// ---------------------------------------------------------------------------
__global__ __launch_bounds__(512, 2) void simmin_kernel(
    const uint8_t* __restrict__ a8, const uint8_t* __restrict__ p8,
    uint32_t* __restrict__ minenc)
{
  __shared__ __attribute__((aligned(16))) uint8_t Alds[2][BM * BK];
  __shared__ __attribute__((aligned(16))) uint8_t Plds[2][BN * BK];
  __shared__ float redmin[2][4][128];

  const int tid  = threadIdx.x;
  const int lane = tid & 63;
  const int wave = tid >> 6;          // 0..7
  const int waveM = wave >> 2;        // 0..1 (row half)
  const int waveN = wave & 3;         // 0..3 (col quarter)
  const int quad = lane >> 4;
  const int l15  = lane & 15;

  // super-tile swizzle (see header comment): bijective over 1024 blocks
  const int bid = blockIdx.x;
  const int blockRow = (bid & 7) * 4 + ((bid >> 3) & 3);  // 0..31
  const int blockCol = bid >> 5;                          // 0..31

  f32x4 acc[8][4];
  const f32x4 zero = {0.f, 0.f, 0.f, 0.f};
#pragma unroll
  for (int i = 0; i < 8; i++)
#pragma unroll
    for (int j = 0; j < 4; j++) acc[i][j] = zero;

  // staging: chunk = 8 rows x 128B; lane i: row = i/8, XOR-swizzled k-slot
  // fetched pre-swizzled on the global side (LDS side must stay contiguous).
  const int srow = lane >> 3;
  const int sk   = (lane & 7) ^ srow;
  const uint8_t* aBase = a8 + (size_t)(blockRow * BM) * D_DIM;
  const uint8_t* pBase = p8 + (size_t)(blockCol * BN) * D_DIM;

  // stage one half-tile (128 rows of A and P) of K-tile t into buf.
  // 16 chunks of 8 rows; each thread: 2 chunks x 2 arrays = 4 loads.
  auto stage_half = [&](int t, int h, int buf) {
#pragma unroll
    for (int c = 0; c < 2; c++) {
      const int chunk = h * 16 + wave * 2 + c;   // h*16 .. h*16+15
      const size_t goff = (size_t)(chunk * 8 + srow) * D_DIM + t * BK + sk * 16;
      load16_to_lds(aBase + goff, &Alds[buf][chunk * 1024]);
      load16_to_lds(pBase + goff, &Plds[buf][chunk * 1024]);
    }
  };

  auto read_af = [&](int buf, int mf) -> i32x8 {
    const int r = waveM * 128 + mf * 16 + l15;
    const int rx = r & 7;
    const int4 lo = *(const int4*)&Alds[buf][r * BK + (((quad * 2 + 0) ^ rx) * 16)];
    const int4 hi = *(const int4*)&Alds[buf][r * BK + (((quad * 2 + 1) ^ rx) * 16)];
    return (i32x8){lo.x, lo.y, lo.z, lo.w, hi.x, hi.y, hi.z, hi.w};
  };
  auto read_bf = [&](int buf, int nf) -> i32x8 {
    const int r = waveN * 64 + nf * 16 + l15;
    const int rx = r & 7;
    const int4 lo = *(const int4*)&Plds[buf][r * BK + (((quad * 2 + 0) ^ rx) * 16)];
    const int4 hi = *(const int4*)&Plds[buf][r * BK + (((quad * 2 + 1) ^ rx) * 16)];
    return (i32x8){lo.x, lo.y, lo.z, lo.w, hi.x, hi.y, hi.z, hi.w};
  };

#define MFMA_ROW(mf_, af_)                                                    \
  _Pragma("unroll")                                                           \
  for (int nf = 0; nf < 4; nf++)                                              \
    acc[mf_][nf] = __builtin_amdgcn_mfma_scale_f32_16x16x128_f8f6f4(          \
        af_, bfr[nf], acc[mf_][nf], 0, 0, 0, 0x7F7F7F7F, 0, 0x7F7F7F7F);

  // prologue: stage K-tiles 0 and 1 (16 loads/thread); wait own t0 loads
  // (vmcnt(8) leaves t1's 8 in flight); barrier -> everyone's t0 complete.
  stage_half(0, 0, 0); stage_half(0, 1, 0);
  stage_half(1, 0, 1); stage_half(1, 1, 1);
  asm volatile("s_waitcnt vmcnt(8)" ::: "memory");
  __builtin_amdgcn_s_barrier();

#pragma unroll
  for (int t = 0; t < 4; t++) {
    const int buf = t & 1;

    // ---- phase 0: bfr + af0..3 reads | stage | bar | 16 MFMA | bar
    i32x8 bfr[4];
#pragma unroll
    for (int nf = 0; nf < 4; nf++) bfr[nf] = read_bf(buf, nf);
    i32x8 af0 = read_af(buf, 0), af1 = read_af(buf, 1);
    i32x8 af2 = read_af(buf, 2), af3 = read_af(buf, 3);
    if (t == 1) stage_half(2, 0, 0);
    if (t == 2) stage_half(3, 0, 1);
    __builtin_amdgcn_s_barrier();
    __builtin_amdgcn_s_setprio(1);
    MFMA_ROW(0, af0);
    MFMA_ROW(1, af1);
    MFMA_ROW(2, af2);
    MFMA_ROW(3, af3);
    __builtin_amdgcn_s_setprio(0);
    __builtin_amdgcn_s_barrier();

    // ---- phase 1: af4..7 reads | stage | bar | 16 MFMA | vmcnt tail | bar
    i32x8 af4 = read_af(buf, 4), af5 = read_af(buf, 5);
    i32x8 af6 = read_af(buf, 6), af7 = read_af(buf, 7);
    if (t == 1) stage_half(2, 1, 0);
    if (t == 2) stage_half(3, 1, 1);
    __builtin_amdgcn_s_barrier();
    __builtin_amdgcn_s_setprio(1);
    MFMA_ROW(4, af4);
    MFMA_ROW(5, af5);
    MFMA_ROW(6, af6);
    MFMA_ROW(7, af7);
    __builtin_amdgcn_s_setprio(0);
    if (t < 3) asm volatile("s_waitcnt vmcnt(0)" ::: "memory");
    __builtin_amdgcn_s_barrier();
  }
#undef MFMA_ROW

  // ---- fused epilogue: per-row min over this block's 256 cols, diag masked
  const int rowTileBase = blockRow * BM + waveM * 128;
  const int colTileBase = blockCol * BN + waveN * 64;

  float rm[8][4];
#pragma unroll
  for (int mf = 0; mf < 8; mf++)
#pragma unroll
    for (int r = 0; r < 4; r++) rm[mf][r] = 3.0e38f;

#pragma unroll
  for (int mf = 0; mf < 8; mf++) {
#pragma unroll
    for (int nf = 0; nf < 4; nf++) {
      const int col = colTileBase + nf * 16 + l15;
#pragma unroll
      for (int r = 0; r < 4; r++) {
        const int row = rowTileBase + mf * 16 + quad * 4 + r;
        const float v = acc[mf][nf][r];
        rm[mf][r] = (row == col) ? rm[mf][r] : fminf(rm[mf][r], v);
      }
    }
  }
  // fold across the 16 lanes of each l15-group (cols congruent mod 16)
#pragma unroll
  for (int d = 1; d < 16; d <<= 1)
#pragma unroll
    for (int mf = 0; mf < 8; mf++)
#pragma unroll
      for (int r = 0; r < 4; r++)
        rm[mf][r] = fminf(rm[mf][r], __shfl_xor(rm[mf][r], d));

  // each wave: 128 row-mins over its 64 cols -> LDS slice [waveM][waveN]
  if (l15 == 0) {
#pragma unroll
    for (int mf = 0; mf < 8; mf++)
#pragma unroll
      for (int r = 0; r < 4; r++)
        redmin[waveM][waveN][mf * 16 + quad * 4 + r] = rm[mf][r];
  }
  __syncthreads();

  // fold 4 waveN slices; tid = waveM_r*128 + local row
  if (tid < 256) {
    const int wm = tid >> 7, idx = tid & 127;
    const float m = fminf(fminf(redmin[wm][0][idx], redmin[wm][1][idx]),
                          fminf(redmin[wm][2][idx], redmin[wm][3][idx]));
    atomicMin(&minenc[blockRow * BM + tid], enc_f32(m));  // device-scope
  }
}

// ---------------------------------------------------------------------------
// Kernel 3: single block (1024 thr) — decode row-mins, loss, mean, store.
// Separate launch: kernel-boundary coherence makes plain loads correct
// (verified R0-R2); per-block device fences inside simmin cost ~340us (R3/R4).
// ---------------------------------------------------------------------------
__global__ __launch_bounds__(1024) void finalize_kernel(
    const uint32_t* __restrict__ minenc, const float* __restrict__ cos_ap,
    float* __restrict__ out)
{
  float sum = 0.0f;
#pragma unroll
  for (int r = threadIdx.x; r < B_ROWS; r += 1024)
    sum += fmaxf(0.0f, 1.0f + cos_ap[r] - dec_f32(minenc[r]));

#pragma unroll
  for (int d = 1; d < 64; d <<= 1) sum += __shfl_xor(sum, d);
  __shared__ float s[16];
  if ((threadIdx.x & 63) == 0) s[threadIdx.x >> 6] = sum;
  __syncthreads();
  if (threadIdx.x < 64) {
    float t = (threadIdx.x < 16) ? s[threadIdx.x] : 0.0f;
#pragma unroll
    for (int d = 1; d < 16; d <<= 1) t += __shfl_xor(t, d);
    if (threadIdx.x == 0) out[0] = t * (1.0f / (float)B_ROWS);
  }
}

// ---------------------------------------------------------------------------
extern "C" void kernel_launch(void* const* d_in, const int* in_sizes, int n_in,
                              void* d_out, int out_size, void* d_ws, size_t ws_size,
                              hipStream_t stream) {
  const float* anchor   = (const float*)d_in[0];
  const float* positive = (const float*)d_in[1];

  char* ws = (char*)d_ws;
  uint32_t* a8     = (uint32_t*)(ws);                                // 4 MB
  uint32_t* p8     = (uint32_t*)(ws + (4ull << 20));                 // 4 MB
  float*    cos_ap = (float*)(ws + (8ull << 20));                    // 32 KB
  uint32_t* minenc = (uint32_t*)(ws + (8ull << 20) + (32ull << 10)); // 32 KB
  float*    out = (float*)d_out;

  norm_kernel<<<B_ROWS / 4, 256, 0, stream>>>(anchor, positive, a8, p8,
                                              cos_ap, minenc);
  simmin_kernel<<<N_BLOCKS, 512, 0, stream>>>((const uint8_t*)a8,
                                              (const uint8_t*)p8, minenc);
  finalize_kernel<<<1, 1024, 0, stream>>>(minenc, cos_ap, out);
}